// Round 1
// 664.852 us; speedup vs baseline: 1.0456x; 1.0456x over previous
//
#include <hip/hip_runtime.h>

#define NEGF (-1e30f)

constexpr int S = 512;
constexpr int L = 32;

// One block per batch. 256 threads: cur = t>>3 (0..31), jg = t&7.
// R6: pipelined lead/lag restructure.
//   alpha[f][c] = LSE( lag(f) , beta[f-1][c] + seg[f,f,c] )        (j=1 is "lead")
//   lag(f)      = LSE_{j=2..64} beta[f-j][c] + seg[f-j+1,f,c]*j + diag[c]*(j-1)
//   beta[p][c]  = LSE_prev( alpha[p][prev] + T[prev][c] )
// lag(f) only needs beta[<=f-2], so it is computed one step AHEAD of the lead
// and carried in registers (GR8 leaves the reduce in all 8 lanes of the group).
// Critical chain per step is now just: phase2 -> reg j=1 merge -> barrier -> phase2.
//  - alpha crosses the barrier as a (max,sum) pair: no log/exp round-trip.
//  - beta stays log-form in the ring (keeps sums bounded <= 65; no overflow drift).
//  - j=2 term uses register bm (beta[k-1]) instead of the just-written ring row;
//    its LDS read is redirected to dummy row 64 (= -inf).  Ring row 63 is
//    pre-initialized to 0 and acts as beta[-1]=0 (the initial-segment term).
//  - ring store moved into the NEXT step's lead (off phase2's tail);
//    lag COMPUTE (pure VALU, operands in regs) placed after the barrier to fill
//    phase2's ds_read_b128 + exp/log latency.

template <int CTRL>
__device__ __forceinline__ float dppf(float x) {
    return __builtin_bit_cast(float,
        __builtin_amdgcn_update_dpp(0, __builtin_bit_cast(int, x),
                                    CTRL, 0xf, 0xf, true));
}
// 8-lane-group reduce, result valid in ALL 8 lanes ({xor1,xor2,xor7}).
#define GR8_MAX(v) do { v = fmaxf(v, dppf<0xB1>(v));   /* quad_perm xor1 */ \
                        v = fmaxf(v, dppf<0x4E>(v));   /* quad_perm xor2 */ \
                        v = fmaxf(v, dppf<0x141>(v)); } while (0) /* row_half_mirror = xor7 */
#define GR8_ADD(v) do { v += dppf<0xB1>(v);                                 \
                        v += dppf<0x4E>(v);                                 \
                        v += dppf<0x141>(v); } while (0)

// LDS-only workgroup barrier: orders LDS, does NOT drain vmcnt (prefetches fly).
#define LDS_BARRIER() do {                                                  \
    __builtin_amdgcn_fence(__ATOMIC_RELEASE, "workgroup", "local");         \
    __builtin_amdgcn_s_barrier();                                           \
    __builtin_amdgcn_fence(__ATOMIC_ACQUIRE, "workgroup", "local");         \
} while (0)

// seg column prefetch for lag frame f: sv[i] = seg[st, f, cur], st = f-j0+1, j0 = jg*8+i+2
#define PF_LAG(dst, f_) do {                                                \
    int fe2 = (f_); if (fe2 > S - 1) fe2 = S - 1;                           \
    _Pragma("unroll")                                                       \
    for (int i = 0; i < 8; ++i) {                                           \
        const int j0 = jg * 8 + i + 2;                                      \
        int st = fe2 - j0 + 1; st = st < 0 ? 0 : st;                        \
        dst[i] = segB[((size_t)st * S + fe2) * L];                          \
    }                                                                       \
} while (0)

// diagonal element seg[f,f,cur] for the lead (j=1) term
#define PF_S1(dst, f_) do {                                                 \
    int fe2 = (f_); if (fe2 > S - 1) fe2 = S - 1;                           \
    dst = segB[(size_t)fe2 * (S + 1) * L];                                  \
} while (0)

// ring loads for lag frame f (j = jg*8+i+2).  j=2 slot (jg==0,i==0) and masked
// slots are redirected to dummy row 64 (-inf).  Valid j needs j <= lim where
// lim = min(f+1, 64); j == f+1 lands on row 63 (= beta[-1] = 0, init segment).
#define LAGLOAD(f_, lim_, rr) do {                                          \
    const int f_v = (f_); const int lim_v = (lim_);                         \
    _Pragma("unroll")                                                       \
    for (int i = 0; i < 8; ++i) {                                           \
        const int j0 = jg * 8 + i + 2;                                      \
        int row = (f_v - j0) & 63;                                          \
        if (j0 > lim_v || (i == 0 && jg == 0)) row = 64;                    \
        rr[i] = ring[row * 33 + cur];                                       \
    }                                                                       \
} while (0)

// lead for frame k: merge lag partial (pM,pS) with the j=1 term; write alpha
// (max,sum) pair for phase2, and store beta[k-1] (=bm) into the ring.
#define LEAD(k_, s1v_) do {                                                 \
    const float t1m = bm + (s1v_);                                          \
    const float Ma  = fmaxf(pM, t1m);                                       \
    const float Sa  = pS * __expf(pM - Ma) + __expf(t1m - Ma);              \
    if (jg == 0) {                                                          \
        *(float2*)&aMS[(k_)&1][cur * 2] = make_float2(Ma, Sa);              \
        ring[(((k_) - 1) & 63) * 33 + cur] = bm;                            \
    }                                                                       \
} while (0)

// lag compute: pure VALU (no LDS) -> placed post-barrier to fill phase2 stalls.
// jg==0 overrides tt[0] with the register j=2 term (bm = beta[f-2]).
#define LAGCOMP(sv, rr) do {                                                \
    float tt[8];                                                            \
    _Pragma("unroll")                                                       \
    for (int i = 0; i < 8; ++i)                                             \
        tt[i] = rr[i] + fmaf(sv[i], jf[i], dj[i]);                          \
    if (jg == 0) tt[0] = bm + fmaf(sv[0], jf[0], dj[0]);                    \
    float M = fmaxf(fmaxf(fmaxf(tt[0],tt[1]), fmaxf(tt[2],tt[3])),          \
                    fmaxf(fmaxf(tt[4],tt[5]), fmaxf(tt[6],tt[7])));         \
    GR8_MAX(M);                                                             \
    float SS = ((__expf(tt[0]-M) + __expf(tt[1]-M)) +                       \
                (__expf(tt[2]-M) + __expf(tt[3]-M))) +                      \
               ((__expf(tt[4]-M) + __expf(tt[5]-M)) +                       \
                (__expf(tt[6]-M) + __expf(tt[7]-M)));                       \
    GR8_ADD(SS);                                                            \
    pM = M; pS = SS;                                                        \
} while (0)

// phase2 for frame k: beta[k][cur] from the alpha (max,sum) pairs. One log.
#define PHASE2(k_) do {                                                     \
    const int par = (k_) & 1;                                               \
    const float4 A0 = *(const float4*)&aMS[par][jg * 8];                    \
    const float4 A1 = *(const float4*)&aMS[par][jg * 8 + 4];                \
    float mx = fmaxf(fmaxf(A0.x, A0.z), fmaxf(A1.x, A1.z));                 \
    GR8_MAX(mx);                                                            \
    float sb = (A0.y * E0) * __expf(A0.x - mx) +                            \
               (A0.w * E1) * __expf(A0.z - mx) +                            \
               (A1.y * E2) * __expf(A1.x - mx) +                            \
               (A1.w * E3) * __expf(A1.z - mx);                             \
    GR8_ADD(sb);                                                            \
    bm = mx + __logf(sb);                                                   \
} while (0)

#define STEP(k_, sv, s1v_, lim_) do {                                       \
    float rr[8];                                                            \
    LAGLOAD((k_) + 1, lim_, rr);                                            \
    LEAD(k_, s1v_);                                                         \
    LDS_BARRIER();                                                          \
    LAGCOMP(sv, rr);                                                        \
    PHASE2(k_);                                                             \
} while (0)

#define LIMV(kk) (((kk) + 2) < 64 ? ((kk) + 2) : 64)

__launch_bounds__(256, 1)
__global__ void semicrf_fwd(const float* __restrict__ seg,
                            const float* __restrict__ trans,
                            float* __restrict__ out)
{
    const int t   = threadIdx.x;
    const int b   = blockIdx.x;
    const int cur = t >> 3;
    const int jg  = t & 7;

    __shared__ float ring[65 * 33];            // log-beta; row 63 = beta[-1] = 0, row 64 = -inf
    __shared__ __align__(16) float aMS[2][64]; // alpha (max,sum), parity-buffered

    const float diag_c = trans[cur * 33];                // trans[cur][cur]
    const float E0 = __expf(trans[(jg * 4 + 0) * 32 + cur]);
    const float E1 = __expf(trans[(jg * 4 + 1) * 32 + cur]);
    const float E2 = __expf(trans[(jg * 4 + 2) * 32 + cur]);
    const float E3 = __expf(trans[(jg * 4 + 3) * 32 + cur]);

    float jf[8], dj[8];
    #pragma unroll
    for (int i = 0; i < 8; ++i) {
        const int j0 = jg * 8 + i + 2;
        jf[i] = (float)j0;
        dj[i] = diag_c * (float)(j0 - 1);
    }

    const float* segB = seg + (size_t)b * S * S * L + cur;

    // prefetch pipeline: lag frame f lives in sv[f&3], lead scalar in s1[f&3].
    float sv0[8], sv1[8], sv2[8], sv3[8];
    float s10, s11, s12, s13;
    PF_LAG(sv1, 1); PF_LAG(sv2, 2); PF_LAG(sv3, 3); PF_LAG(sv0, 4);
    PF_S1(s11, 1);  PF_S1(s12, 2);  PF_S1(s13, 3);  PF_S1(s10, 4);

    if (t < 32) {
        ring[63 * 33 + t] = 0.0f;   // beta[-1] = 0  (initial-segment source)
        ring[64 * 33 + t] = NEGF;   // dummy row for masked slots
    }
    if (jg == 0) {                  // alpha[0][c] = seg[b,0,0,c], sum = 1
        const float a0 = segB[0];
        *(float2*)&aMS[0][cur * 2] = make_float2(a0, 1.0f);
    }
    __syncthreads();

    float pM = NEGF, pS = 0.0f, bm = 0.0f;  // bm = beta[-1] = 0 for lag(1)'s j=2

    { // step 0: lag(1) + phase2(0)   (alpha[0] was written above)
        float rr[8];
        LAGLOAD(1, 2, rr);
        LDS_BARRIER();
        LAGCOMP(sv1, rr);
        PHASE2(0);
    }
    PF_LAG(sv1, 5);

    // EARLY: k = 1..64 (lag frames 2..65 need the dynamic j <= f+1 mask)
    for (int k = 1; k <= 61; k += 4) {
        STEP(k + 0, sv2, s11, LIMV(k + 0)); PF_LAG(sv2, k + 5); PF_S1(s11, k + 4);
        STEP(k + 1, sv3, s12, LIMV(k + 1)); PF_LAG(sv3, k + 6); PF_S1(s12, k + 5);
        STEP(k + 2, sv0, s13, LIMV(k + 2)); PF_LAG(sv0, k + 7); PF_S1(s13, k + 6);
        STEP(k + 3, sv1, s10, LIMV(k + 3)); PF_LAG(sv1, k + 8); PF_S1(s10, k + 7);
    }
    // CLEAN: k = 65..508 (only the static j=65 slot is masked)
    for (int k = 65; k <= 505; k += 4) {
        STEP(k + 0, sv2, s11, 64); PF_LAG(sv2, k + 5); PF_S1(s11, k + 4);
        STEP(k + 1, sv3, s12, 64); PF_LAG(sv3, k + 6); PF_S1(s12, k + 5);
        STEP(k + 2, sv0, s13, 64); PF_LAG(sv0, k + 7); PF_S1(s13, k + 6);
        STEP(k + 3, sv1, s10, 64); PF_LAG(sv1, k + 8); PF_S1(s10, k + 7);
    }
    STEP(509, sv2, s11, 64);
    STEP(510, sv3, s12, 64);

    { // k = 511: lead only (no phase2 needed)
        const float t1m = bm + s13;
        const float Ma  = fmaxf(pM, t1m);
        const float Sa  = pS * __expf(pM - Ma) + __expf(t1m - Ma);
        if (jg == 0) *(float2*)&aMS[1][cur * 2] = make_float2(Ma, Sa);
    }
    __syncthreads();

    // log_z[b] = LSE_c ( Ma[c] + log Sa[c] ), alpha[511] parity = 1
    if (t < 64) {
        float v  = (t < 32) ? (aMS[1][t * 2] + __logf(aMS[1][t * 2 + 1])) : NEGF;
        float m  = v;
        float ss = 1.f;
        #pragma unroll
        for (int mk = 1; mk <= 32; mk <<= 1) {
            const float m2 = __shfl_xor(m, mk);
            const float s2 = __shfl_xor(ss, mk);
            const float mn = fmaxf(m, m2);
            ss = ss * __expf(m - mn) + s2 * __expf(m2 - mn);
            m  = mn;
        }
        if (t == 0) out[b] = m + __logf(ss);
    }
}

extern "C" void kernel_launch(void* const* d_in, const int* in_sizes, int n_in,
                              void* d_out, int out_size, void* d_ws, size_t ws_size,
                              hipStream_t stream) {
    const float* seg   = (const float*)d_in[0];   // [8, 512, 512, 32] fp32
    const float* trans = (const float*)d_in[1];   // [32, 32] fp32
    float* out = (float*)d_out;                   // [8] fp32
    hipLaunchKernelGGL(semicrf_fwd, dim3(8), dim3(256), 0, stream,
                       seg, trans, out);
}